// Round 2
// baseline (2308.904 us; speedup 1.0000x reference)
//
#include <hip/hip_runtime.h>
#include <stdint.h>

// Problem constants: B=64, S=512, IN_F=HID=OUT_F=1024
typedef __attribute__((ext_vector_type(8))) short short8_t;   // 8 x bf16 MFMA frag
typedef __attribute__((ext_vector_type(4))) float f32x4_t;    // MFMA acc
typedef __attribute__((ext_vector_type(4))) unsigned int u32x4_t;  // 16B tagged line

__device__ __forceinline__ unsigned short f2bf_u(float f) {
  unsigned int u = __float_as_uint(f);
  unsigned int r = (u + 0x7fff + ((u >> 16) & 1)) >> 16;  // RNE
  return (unsigned short)r;
}
__device__ __forceinline__ float bf2f(unsigned short s) {
  return __uint_as_float(((unsigned int)s) << 16);
}
__device__ __forceinline__ short8_t pack8(float4 a, float4 b) {
  short8_t r;
  r[0]=(short)f2bf_u(a.x); r[1]=(short)f2bf_u(a.y); r[2]=(short)f2bf_u(a.z); r[3]=(short)f2bf_u(a.w);
  r[4]=(short)f2bf_u(b.x); r[5]=(short)f2bf_u(b.y); r[6]=(short)f2bf_u(b.z); r[7]=(short)f2bf_u(b.w);
  return r;
}
__device__ __forceinline__ void gl_lds16(const void* g, void* l) {
  __builtin_amdgcn_global_load_lds(
      (const __attribute__((address_space(1))) unsigned int*)g,
      (__attribute__((address_space(3))) unsigned int*)l, 16, 0, 0);
}

// ---------------- prep: x fp32 -> bf16 (8 elems/thread) ----------------
__global__ void k_prep_x(const float* __restrict__ src, unsigned short* __restrict__ dst) {
  int i = blockIdx.x * blockDim.x + threadIdx.x;          // 4194304 threads
  if (i >= 4194304) return;
  const float4* s = (const float4*)src + (size_t)i * 2;
  float4 a = s[0], b = s[1];
  *(short8_t*)(dst + (size_t)i * 8) = pack8(a, b);
}

// ------- prep: W_x, W_ho -> bf16 [N][K]; zero hx lines + XCD table -------
__global__ void k_prep_w(const float* __restrict__ Wih, const float* __restrict__ Who,
                         unsigned short* __restrict__ Wxbf, unsigned short* __restrict__ Whobf,
                         u32x4_t* __restrict__ hx) {
  int tid = blockIdx.x * blockDim.x + threadIdx.x;        // 262144 threads
  if (tid < 131072) {            // W_x = W_ih[:, 0:1024]
    int n = tid >> 7, c = tid & 127;
    const float* s = Wih + (size_t)n * 2048 + c * 8;
    float4 a = *(const float4*)s, b = *(const float4*)(s + 4);
    *(short8_t*)(Wxbf + (size_t)n * 1024 + c * 8) = pack8(a, b);
  } else {
    int j = tid - 131072;        // W_ho
    int n = j >> 7, c = j & 127;
    const float* s = Who + (size_t)n * 1024 + c * 8;
    float4 a = *(const float4*)s, b = *(const float4*)(s + 4);
    *(short8_t*)(Whobf + (size_t)n * 1024 + c * 8) = pack8(a, b);
  }
  if (tid < 32784) {             // 512KB hx (2 slot x 8 g x 8 rank x 4KB) + 256B table
    u32x4_t z; z[0] = 0; z[1] = 0; z[2] = 0; z[3] = 0;
    hx[tid] = z;
  }
}

// ---------------- GEMM: C[MxN] = A[MxK] @ Bw[NxK]^T + bias, bf16 MFMA ----------------
template <bool OUT_BF16>
__global__ __launch_bounds__(256, 2) void k_gemm_bt(
    const unsigned short* __restrict__ A, const unsigned short* __restrict__ Bw,
    const float* __restrict__ bias, void* __restrict__ Cout) {
  constexpr int K = 1024, N = 1024;
  __shared__ unsigned short sm[8192];   // bytes [0,8K): A-tile, [8K,16K): B-tile
  const int tid = threadIdx.x;
  const int wave = tid >> 6, lane = tid & 63;
  const int tm = blockIdx.y * 128, tn = blockIdx.x * 128;
  const int wm = wave >> 1, wn = wave & 1;

  f32x4_t acc[4][4];
#pragma unroll
  for (int i = 0; i < 4; i++)
#pragma unroll
    for (int j = 0; j < 4; j++) acc[i][j] = (f32x4_t){0.f, 0.f, 0.f, 0.f};

  char* ldsA = (char*)sm;
  char* ldsB = (char*)sm + 8192;
  const int cc = ((lane & 3) ^ ((lane >> 3) & 3)) * 8;  // swizzled k-chunk (elements)
  const int rs = lane >> 2;                             // row within 16-row group

  for (int k0 = 0; k0 < K; k0 += 32) {
    __syncthreads();
#pragma unroll
    for (int c = 0; c < 2; c++) {
      int r0 = c * 64 + wave * 16;                      // wave-uniform
      int r = r0 + rs;
      gl_lds16(A + (size_t)(tm + r) * K + (k0 + cc), ldsA + r0 * 64);
      gl_lds16(Bw + (size_t)(tn + r) * K + (k0 + cc), ldsB + r0 * 64);
    }
    __builtin_amdgcn_s_waitcnt(0);
    __syncthreads();

    short8_t af[4], bf[4];
#pragma unroll
    for (int mt = 0; mt < 4; mt++) {
      int r = wm * 64 + mt * 16 + (lane & 15);
      int slot = (((lane >> 4) ^ (((lane & 15) >> 1) & 3))) * 16;
      af[mt] = *(const short8_t*)(ldsA + r * 64 + slot);
    }
#pragma unroll
    for (int nt = 0; nt < 4; nt++) {
      int r = wn * 64 + nt * 16 + (lane & 15);
      int slot = (((lane >> 4) ^ (((lane & 15) >> 1) & 3))) * 16;
      bf[nt] = *(const short8_t*)(ldsB + r * 64 + slot);
    }
#pragma unroll
    for (int mt = 0; mt < 4; mt++)
#pragma unroll
      for (int nt = 0; nt < 4; nt++)
        acc[mt][nt] = __builtin_amdgcn_mfma_f32_16x16x32_bf16(af[mt], bf[nt], acc[mt][nt], 0, 0, 0);
  }

#pragma unroll
  for (int nt = 0; nt < 4; nt++) {
    int n = tn + wn * 64 + nt * 16 + (lane & 15);
    float bs = bias[n];
#pragma unroll
    for (int mt = 0; mt < 4; mt++) {
      int rowb = tm + wm * 64 + mt * 16 + ((lane >> 4) << 2);
      f32x4_t v = acc[mt][nt];
#pragma unroll
      for (int q = 0; q < 4; q++) {
        float o = v[q] + bs;
        size_t off = (size_t)(rowb + q) * N + n;
        if (OUT_BF16) ((unsigned short*)Cout)[off] = f2bf_u(o);
        else          ((float*)Cout)[off] = o;
      }
    }
  }
}

// ---------------- persistent recurrence, XCD-local exchange ----------------
// 64 blocks x 256 thr. 8 groups x 8 ranks; group = bid&7 (expected XCD under
// round-robin), rank = bid>>3. Group g owns batches [8g,8g+8); rank r owns
// hidden cols [128r,128r+128).
// Exchange: tagged 16B lines [d0,tag,d1,tag], tag=t+1, written TWICE to the
// SAME address: sc0 (lands in producer XCD's L2 via write-through) then
// sc0 sc1 (lands at LLC). Consumers poll per-peer: same-XCD peers (per the
// runtime HW_REG_XCC_ID table) with sc0 loads (L2 hit, ~250cy RT); remote
// peers with sc0 sc1 (LLC). If a "fast" peer doesn't appear within 32 poll
// rounds, pending peers flip to the LLC path -> correctness never depends on
// the blockIdx->XCD mapping, only speed does.
// 2 slots (t&1): producer can only overwrite slot holding h[t] after its step
// t+2 poll, which transitively requires every rank consumed h[t]. Tags
// strictly increase; zero-init kills first-step ABA.
__global__ __launch_bounds__(256, 1) void k_rnn(
    const float* __restrict__ Wih, const float* __restrict__ h0,
    const unsigned short* __restrict__ xproj, unsigned short* __restrict__ Hall,
    char* __restrict__ hx) {
  const int bid = blockIdx.x;
  const int g = bid & 7;                 // group (expected XCD)
  const int rank = bid >> 3;             // 0..7
  const int tid = threadIdx.x;
  const int wave = tid >> 6, lane = tid & 63;
  const int b0 = g * 8;
  const int nw = rank * 128 + wave * 32; // wave's first hidden col

  __shared__ unsigned short hs[16][1032];   // h[t-1]: rows 0..7 = batches, 8..15 = zero pad
  __shared__ unsigned short hsOut[8][132];  // this rank's 128 cols of h[t]
  __shared__ int slowLds;

  // ---- runtime XCD table handshake (one-time, LLC-scope) ----
  {
    int xcd = __builtin_amdgcn_s_getreg(6164);   // hwreg(HW_REG_XCC_ID=20, 0, 4)
    int myval = 256 + (xcd & 15);
    int* table = (int*)(hx + 524288);
    if (tid == 0) {
      __hip_atomic_store(&table[bid], myval, __ATOMIC_RELAXED, __HIP_MEMORY_SCOPE_AGENT);
      int sm = 0;
      for (int j = 0; j < 8; j++) {
        if (j == rank) continue;
        int v;
        do {
          v = __hip_atomic_load(&table[j * 8 + g], __ATOMIC_RELAXED, __HIP_MEMORY_SCOPE_AGENT);
        } while (v < 256);
        if (v != myval) sm |= 1 << j;              // peer on a different XCD -> slow path
      }
      slowLds = sm;
    }
  }

  // ---- W_h preload: 2 col-tiles x 32 k-steps per wave (256 VGPRs) ----
  short8_t bfrag[2][32];
#pragma unroll
  for (int ct = 0; ct < 2; ct++) {
    const int n = nw + ct * 16 + (lane & 15);
    const float* wrow = Wih + (size_t)n * 2048 + 1024 + ((lane >> 4) * 8);
#pragma unroll
    for (int kt = 0; kt < 32; kt++) {
      float4 f0 = *(const float4*)(wrow + kt * 32);
      float4 f1 = *(const float4*)(wrow + kt * 32 + 4);
      bfrag[ct][kt] = pack8(f0, f1);
    }
  }

  // zero A-frag pad rows 8..15 once
  for (int i = tid; i < 4128; i += 256) ((int*)&hs[8][0])[i] = 0;
  __syncthreads();
  const int slowInit = slowLds;

  const int row = tid >> 5, c32 = tid & 31;        // thread's 8B slice: (batch row, 4 cols)
  const char* hxg = hx + g * 32768;                // [slot:262144][g:32768][rank:4096][tid*16]
  const unsigned voffc = (unsigned)(tid * 16);

  for (int t = 0; t < 512; t++) {
    // ---- xproj prefetch (overlaps the poll) ----
    unsigned short xr[2][4];
#pragma unroll
    for (int ct = 0; ct < 2; ct++)
#pragma unroll
      for (int q = 0; q < 4; q++) {
        int bl = (((lane >> 4) << 2) + q) & 7;     // clamp keeps address in-bounds
        xr[ct][q] = xproj[((size_t)(b0 + bl) * 512 + t) * 1024 + nw + ct * 16 + (lane & 15)];
      }

    if (t > 0) {
      // own 128-col chunk: LDS -> LDS
      *(unsigned long long*)&hs[row][rank * 128 + c32 * 4] =
          *(const unsigned long long*)&hsOut[row][c32 * 4];
      const unsigned tg = (unsigned)t;             // h[t-1] carries tag t
      const unsigned sb = ((t - 1) & 1) ? 262144u : 0u;
      unsigned pend = 0xFFu & ~(1u << rank);
      int slow = slowInit;
      int rounds = 0;
      u32x4_t rf[8];
#pragma unroll
      for (int j = 0; j < 8; j++) { rf[j][0] = 0; rf[j][1] = 0; rf[j][2] = 0; rf[j][3] = 0; }
      while (pend) {
#pragma unroll
        for (int j = 0; j < 8; j++) {
          if ((pend >> j) & 1) {
            unsigned off = sb + (unsigned)(j * 4096) + voffc;
            if ((slow >> j) & 1)
              asm volatile("global_load_dwordx4 %0, %1, %2 sc0 sc1"
                           : "=v"(rf[j]) : "v"(off), "s"(hxg) : "memory");
            else
              asm volatile("global_load_dwordx4 %0, %1, %2 sc0"
                           : "=v"(rf[j]) : "v"(off), "s"(hxg) : "memory");
          }
        }
        asm volatile("s_waitcnt vmcnt(0)"
                     : "+v"(rf[0]), "+v"(rf[1]), "+v"(rf[2]), "+v"(rf[3]),
                       "+v"(rf[4]), "+v"(rf[5]), "+v"(rf[6]), "+v"(rf[7]));
#pragma unroll
        for (int j = 0; j < 8; j++) {
          if (((pend >> j) & 1) && rf[j][1] == tg && rf[j][3] == tg) {
            *(unsigned long long*)&hs[row][j * 128 + c32 * 4] =
                (unsigned long long)rf[j][0] | ((unsigned long long)rf[j][2] << 32);
            pend &= ~(1u << j);
          }
        }
        if (++rounds == 32) slow = 0xFF;           // timeout -> LLC path (always written)
      }
    } else {
      const float* s = h0 + (size_t)(b0 + row) * 1024 + c32 * 4;
#pragma unroll
      for (int j = 0; j < 8; j++) {
        float4 a = *(const float4*)(s + j * 128);
        unsigned short* d = &hs[row][j * 128 + c32 * 4];
        d[0] = f2bf_u(a.x); d[1] = f2bf_u(a.y); d[2] = f2bf_u(a.z); d[3] = f2bf_u(a.w);
      }
    }
    __syncthreads();

    // ---- MFMA: h[t-1][8 batches] @ W_h^T for this wave's 32 cols ----
    f32x4_t acc0 = {0.f, 0.f, 0.f, 0.f}, acc1 = {0.f, 0.f, 0.f, 0.f};
    {
      const char* abase = (const char*)&hs[lane & 15][0] + ((lane >> 4) * 16);
#pragma unroll
      for (int kt = 0; kt < 32; kt++) {
        short8_t a = *(const short8_t*)(abase + kt * 64);
        acc0 = __builtin_amdgcn_mfma_f32_16x16x32_bf16(a, bfrag[0][kt], acc0, 0, 0, 0);
        acc1 = __builtin_amdgcn_mfma_f32_16x16x32_bf16(a, bfrag[1][kt], acc1, 0, 0, 0);
      }
    }

    // ---- tanh epilogue -> hsOut (acc rows 8..15 are pad, skipped) ----
#pragma unroll
    for (int q = 0; q < 4; q++) {
      int bl = ((lane >> 4) << 2) + q;
      if (bl < 8) {
        float p0 = acc0[q] + bf2f(xr[0][q]);
        float e0 = __expf(2.0f * p0);
        hsOut[bl][wave * 32 + (lane & 15)] = f2bf_u(1.0f - 2.0f / (e0 + 1.0f));
        float p1 = acc1[q] + bf2f(xr[1][q]);
        float e1 = __expf(2.0f * p1);
        hsOut[bl][wave * 32 + 16 + (lane & 15)] = f2bf_u(1.0f - 2.0f / (e1 + 1.0f));
      }
    }
    __syncthreads();

    // ---- publish: tagged line to L2 (sc0) + LLC insurance (sc0 sc1) + Hall ----
    {
      unsigned long long vv = *(const unsigned long long*)&hsOut[row][c32 * 4];
      u32x4_t line;
      line[0] = (unsigned)vv;         line[1] = (unsigned)(t + 1);
      line[2] = (unsigned)(vv >> 32); line[3] = (unsigned)(t + 1);
      unsigned off = ((t & 1) ? 262144u : 0u) + (unsigned)(rank * 4096) + voffc;
      asm volatile("global_store_dwordx4 %0, %1, %2 sc0"
                   :: "v"(off), "v"(line), "s"(hxg) : "memory");
      asm volatile("global_store_dwordx4 %0, %1, %2 sc0 sc1"
                   :: "v"(off), "v"(line), "s"(hxg) : "memory");
      size_t hall_off = ((size_t)(b0 + row) * 512 + t) * 1024 + rank * 128 + c32 * 4;
      *(unsigned long long*)(Hall + hall_off) = vv;
    }
    // fire-and-forget: no trailing barrier, no store-ack drain
  }
}

// ---------------- launch ----------------
extern "C" void kernel_launch(void* const* d_in, const int* in_sizes, int n_in,
                              void* d_out, int out_size, void* d_ws, size_t ws_size,
                              hipStream_t stream) {
  const float* x   = (const float*)d_in[0];   // 64x512x1024
  const float* h0  = (const float*)d_in[1];   // 64x1024
  const float* Wih = (const float*)d_in[2];   // 1024x2048
  const float* bih = (const float*)d_in[3];   // 1024
  const float* Who = (const float*)d_in[4];   // 1024x1024
  const float* bho = (const float*)d_in[5];   // 1024

  char* ws = (char*)d_ws;
  unsigned short* Xbf   = (unsigned short*)ws;                 // 64MB (dead after GEMM1)
  unsigned short* Hall  = (unsigned short*)ws;                 // aliases Xbf
  unsigned short* xproj = (unsigned short*)(ws + 67108864);    // 64MB
  unsigned short* Wxbf  = (unsigned short*)(ws + 134217728);   // 2MB
  unsigned short* Whobf = (unsigned short*)(ws + 136314880);   // 2MB
  char*           hx    = ws + 138412032;                      // 512KB lines + 256B XCD table

  k_prep_x<<<16384, 256, 0, stream>>>(x, Xbf);
  k_prep_w<<<1024, 256, 0, stream>>>(Wih, Who, Wxbf, Whobf, (u32x4_t*)hx);
  k_gemm_bt<true ><<<dim3(8, 256), 256, 0, stream>>>(Xbf, Wxbf, bih, (void*)xproj);
  k_rnn<<<64, 256, 0, stream>>>(Wih, h0, xproj, Hall, hx);
  k_gemm_bt<false><<<dim3(8, 256), 256, 0, stream>>>(Hall, Whobf, bho, d_out);
}